// Round 9
// baseline (407.589 us; speedup 1.0000x reference)
//
#include <hip/hip_runtime.h>
#include <math.h>

#define B_ROWS 65536
#define WDIM 512
#define HDIM 8
#define THREADS 512

// Native clang vector type — __builtin_nontemporal_{load,store} require it.
typedef float native_float4 __attribute__((ext_vector_type(4)));

// ---- DPP cross-lane (VALU pipe; avoids ds_swizzle latency/contention) ----
template<int CTRL, int ROWM>
__device__ __forceinline__ float dpp_mov(float oldv, float x) {
    return __int_as_float(__builtin_amdgcn_update_dpp(
        __float_as_int(oldv), __float_as_int(x), CTRL, ROWM, 0xF, false));
}

// Full-wave (64-lane) sum, broadcast via readlane(63). Order bit-exact vs R0.
__device__ __forceinline__ float wave_sum(float x) {
    x += dpp_mov<0x121, 0xF>(0.f, x);   // row_ror:1
    x += dpp_mov<0x122, 0xF>(0.f, x);   // row_ror:2
    x += dpp_mov<0x124, 0xF>(0.f, x);   // row_ror:4
    x += dpp_mov<0x128, 0xF>(0.f, x);   // row_ror:8  -> row-of-16 sums
    x += dpp_mov<0x142, 0xA>(0.f, x);   // row_bcast15
    x += dpp_mov<0x143, 0xC>(0.f, x);   // row_bcast31 -> lane63 = total
    return __int_as_float(__builtin_amdgcn_readlane(__float_as_int(x), 63));
}

__device__ __forceinline__ float dot8(native_float4 a0, native_float4 a1,
                                      native_float4 b0, native_float4 b1) {
    float s = a0.x * b0.x;
    s = fmaf(a0.y, b0.y, s); s = fmaf(a0.z, b0.z, s); s = fmaf(a0.w, b0.w, s);
    s = fmaf(a1.x, b1.x, s); s = fmaf(a1.y, b1.y, s);
    s = fmaf(a1.z, b1.z, s); s = fmaf(a1.w, b1.w, s);
    return s;
}

// Order-preserving float->uint: y1 < y2  <=>  ford(y1) < ford(y2) (unsigned).
// Positive: set sign bit. Negative: flip all bits. 3 VALU ops.
__device__ __forceinline__ unsigned ford(float f) {
    unsigned b = __float_as_uint(f);
    return b ^ ((unsigned)((int)b >> 31) | 0x80000000u);
}

// Measured model (R0-R8): resident waves step at the 64/128 VGPR quanta only:
// VGPR<=64 -> 8 waves/SIMD class (occ ~40%), 65..128 -> 4 waves/SIMD (~22%).
// R5/R8 proved <=64 (and even 85-cap) spills; R7 (2-row, VGPR=108, clean,
// 171us, VALUBusy 45%) is the occupancy optimum. Lever now: serial chains.
// R9: (1) y-space top-k — p = exp(y-m)/s is monotone in y (m,s wave-uniform)
// so select the top-14 set directly on order-transformed y bits: DELETES the
// fmax trees, both wave_max DPP chains, and all 16 expf. Tie-exposure is the
// SAME rank-boundary-ulp class R7 already verified (absmax 0.0). (2) radix-4
// bit-search (2 bits/step, 3 parallel thresholds): depth 28 -> 16 steps;
// count chains independent (VALU) and select logic rides SALU.
__global__ __launch_bounds__(THREADS, 2)
void fused_mlp_topk(const float* __restrict__ x,
                    const float* __restrict__ W1,
                    const float* __restrict__ b1,
                    const float* __restrict__ W2,
                    const float* __restrict__ b2,
                    const float* __restrict__ W3,
                    const float* __restrict__ b3,
                    float* __restrict__ out)
{
    // W1 as [j][i] (8x512), W3 transposed to [k][i] (8x512): compute reads are
    // 16B/lane stride-16B ds_read_b128 (conflict-free). One read serves 2 rows.
    __shared__ __align__(16) float sW1[HDIM * WDIM];
    __shared__ __align__(16) float sW3t[HDIM * WDIM];
    __shared__ __align__(16) float sb3[WDIM];

    const int tid = threadIdx.x;
    for (int i = tid; i < HDIM * WDIM; i += THREADS) sW1[i] = W1[i];
    for (int i = tid; i < HDIM * WDIM; i += THREADS) {
        int r = i >> 3, k = i & 7;          // W3 is (512,8) row-major
        sW3t[k * WDIM + r] = W3[i];
    }
    for (int i = tid; i < WDIM; i += THREADS) sb3[i] = b3[i];
    __syncthreads();

    const int lane = tid & 63;
    const int wave_id = blockIdx.x * (THREADS / 64) + (tid >> 6);   // 8192 waves

    const native_float4* sW1v = reinterpret_cast<const native_float4*>(sW1);
    const native_float4* sW3v = reinterpret_cast<const native_float4*>(sW3t);
    const native_float4* sb3v = reinterpret_cast<const native_float4*>(sb3);

    // Preload first row pair (rows ra, ra+1), non-temporal (read-once stream).
    int ra = wave_id * 2;
    const native_float4* xpa = reinterpret_cast<const native_float4*>(x + (size_t)ra * WDIM);
    const native_float4* xpb = xpa + (WDIM / 4);
    native_float4 xa0 = __builtin_nontemporal_load(xpa + lane);
    native_float4 xa1 = __builtin_nontemporal_load(xpa + lane + 64);
    native_float4 xb0 = __builtin_nontemporal_load(xpb + lane);
    native_float4 xb1 = __builtin_nontemporal_load(xpb + lane + 64);

    #pragma unroll 1
    for (int it = 0; it < 4; ++it) {        // 8192 waves * 2 rows * 4 = 65536
        // -------- layer 1: 8 dots of 512 per row; LDS reads shared --------
        float pa[HDIM], pb[HDIM];
        #pragma unroll
        for (int j = 0; j < HDIM; ++j) {
            native_float4 w0 = sW1v[j * 128 + lane];
            native_float4 w1 = sW1v[j * 128 + lane + 64];
            pa[j] = dot8(xa0, xa1, w0, w1);
            pb[j] = dot8(xb0, xb1, w0, w1);
        }
        float h1a[HDIM], h1b[HDIM];
        #pragma unroll
        for (int j = 0; j < HDIM; ++j) {
            float sa = wave_sum(pa[j]) + b1[j];
            float sb = wave_sum(pb[j]) + b1[j];
            h1a[j] = sa > 0.f ? sa : 0.f;
            h1b[j] = sb > 0.f ? sb : 0.f;
        }

        // -------- layer 2: 8x8, wave-uniform --------
        float h2a[HDIM], h2b[HDIM];
        #pragma unroll
        for (int j = 0; j < HDIM; ++j) {
            float va = b2[j], vb = b2[j];
            #pragma unroll
            for (int k = 0; k < HDIM; ++k) {
                const float w = W2[j * HDIM + k];
                va = fmaf(w, h1a[k], va);
                vb = fmaf(w, h1b[k], vb);
            }
            h2a[j] = va > 0.f ? va : 0.f;
            h2b[j] = vb > 0.f ? vb : 0.f;
        }

        // -------- layer 3: vector form -> per-element FMA (contracted),
        // packable into v_pk_fma_f32 --------
        native_float4 ya0 = sb3v[lane];
        native_float4 ya1 = sb3v[lane + 64];
        native_float4 yb0 = ya0, yb1 = ya1;
        #pragma unroll
        for (int k = 0; k < HDIM; ++k) {
            const float ha = h2a[k], hb = h2b[k];
            native_float4 w0 = sW3v[k * 128 + lane];
            native_float4 w1 = sW3v[k * 128 + lane + 64];
            ya0 += ha * w0;  ya1 += ha * w1;
            yb0 += hb * w0;  yb1 += hb * w1;
        }

        // -------- prefetch next pair's x (covered by radix select) -------
        const int nra = ra + 16384;         // 8192 waves * 2 rows sweep
        native_float4 nxa0, nxa1, nxb0, nxb1;
        if (it < 3) {
            const native_float4* nxpa = reinterpret_cast<const native_float4*>(x + (size_t)nra * WDIM);
            const native_float4* nxpb = nxpa + (WDIM / 4);
            nxa0 = __builtin_nontemporal_load(nxpa + lane);
            nxa1 = __builtin_nontemporal_load(nxpa + lane + 64);
            nxb0 = __builtin_nontemporal_load(nxpb + lane);
            nxb1 = __builtin_nontemporal_load(nxpb + lane + 64);
        }

        // -------- y-space top-k: NO max, NO exp, NO div. p = exp(y-m)/s is
        // monotone in y (m,s wave-uniform) => top-14 set of p == top-14 set
        // of y. Order-preserving bit transform, then select on u32. Forced
        // cols 0/511 are the 2 global maxima of p -> threshold = 14th
        // largest of the remaining 510; zero their keys (real y's transform
        // to u >= 0x007FFFFF > 0, so 0 never counts), force mask at emit.
        unsigned ua[8], ub[8];
        ua[0] = ford(ya0.x); ua[1] = ford(ya0.y); ua[2] = ford(ya0.z); ua[3] = ford(ya0.w);
        ua[4] = ford(ya1.x); ua[5] = ford(ya1.y); ua[6] = ford(ya1.z); ua[7] = ford(ya1.w);
        ub[0] = ford(yb0.x); ub[1] = ford(yb0.y); ub[2] = ford(yb0.z); ub[3] = ford(yb0.w);
        ub[4] = ford(yb1.x); ub[5] = ford(yb1.y); ub[6] = ford(yb1.z); ub[7] = ford(yb1.w);
        if (lane == 0)  { ua[0] = 0u; ub[0] = 0u; }   // global col 0
        if (lane == 63) { ua[7] = 0u; ub[7] = 0u; }   // global col 511

        // -------- exact 14th-largest via radix-4 bit-search: 16 steps of
        // 2 bits, 3 parallel thresholds/step (independent count chains).
        // Counts are wave-uniform (ballot) -> digit select on SALU. Two
        // rows' chains also independent -> 6-way count ILP per step. ------
        unsigned Ua = 0u, Ub = 0u;
        for (int b = 30; b >= 0; b -= 2) {
            const unsigned ca1 = Ua | (1u << b), ca2 = Ua | (2u << b), ca3 = Ua | (3u << b);
            const unsigned cb1 = Ub | (1u << b), cb2 = Ub | (2u << b), cb3 = Ub | (3u << b);
            int na1 = 0, na2 = 0, na3 = 0, nb1 = 0, nb2 = 0, nb3 = 0;
            #pragma unroll
            for (int t = 0; t < 8; ++t) {
                na1 += __popcll(__ballot(ua[t] > ca1));
                na2 += __popcll(__ballot(ua[t] > ca2));
                na3 += __popcll(__ballot(ua[t] > ca3));
                nb1 += __popcll(__ballot(ub[t] > cb1));
                nb2 += __popcll(__ballot(ub[t] > cb2));
                nb3 += __popcll(__ballot(ub[t] > cb3));
            }
            const unsigned da = (na3 >= 14) ? 3u : (na2 >= 14) ? 2u : (na1 >= 14) ? 1u : 0u;
            const unsigned db = (nb3 >= 14) ? 3u : (nb2 >= 14) ? 2u : (nb1 >= 14) ? 1u : 0u;
            Ua |= da << b;
            Ub |= db << b;
        }
        const unsigned thra = Ua + 1u;      // mask = u > Ua  <=>  u >= Ua+1
        const unsigned thrb = Ub + 1u;

        // -------- emit 0/1 masks; forced cols overridden ----------
        native_float4 r0, r1, q0, q1;
        r0.x = ua[0] >= thra ? 1.f : 0.f;  r0.y = ua[1] >= thra ? 1.f : 0.f;
        r0.z = ua[2] >= thra ? 1.f : 0.f;  r0.w = ua[3] >= thra ? 1.f : 0.f;
        r1.x = ua[4] >= thra ? 1.f : 0.f;  r1.y = ua[5] >= thra ? 1.f : 0.f;
        r1.z = ua[6] >= thra ? 1.f : 0.f;  r1.w = ua[7] >= thra ? 1.f : 0.f;
        q0.x = ub[0] >= thrb ? 1.f : 0.f;  q0.y = ub[1] >= thrb ? 1.f : 0.f;
        q0.z = ub[2] >= thrb ? 1.f : 0.f;  q0.w = ub[3] >= thrb ? 1.f : 0.f;
        q1.x = ub[4] >= thrb ? 1.f : 0.f;  q1.y = ub[5] >= thrb ? 1.f : 0.f;
        q1.z = ub[6] >= thrb ? 1.f : 0.f;  q1.w = ub[7] >= thrb ? 1.f : 0.f;
        if (lane == 0)  { r0.x = 1.f; q0.x = 1.f; }
        if (lane == 63) { r1.w = 1.f; q1.w = 1.f; }

        native_float4* oa = reinterpret_cast<native_float4*>(out + (size_t)ra * WDIM);
        native_float4* ob = oa + (WDIM / 4);
        __builtin_nontemporal_store(r0, oa + lane);
        __builtin_nontemporal_store(r1, oa + lane + 64);
        __builtin_nontemporal_store(q0, ob + lane);
        __builtin_nontemporal_store(q1, ob + lane + 64);

        ra = nra;
        xa0 = nxa0; xa1 = nxa1; xb0 = nxb0; xb1 = nxb1;
    }
}

extern "C" void kernel_launch(void* const* d_in, const int* in_sizes, int n_in,
                              void* d_out, int out_size, void* d_ws, size_t ws_size,
                              hipStream_t stream) {
    const float* x  = (const float*)d_in[0];
    const float* W1 = (const float*)d_in[1];
    const float* b1 = (const float*)d_in[2];
    const float* W2 = (const float*)d_in[3];
    const float* b2 = (const float*)d_in[4];
    const float* W3 = (const float*)d_in[5];
    const float* b3 = (const float*)d_in[6];
    float* out = (float*)d_out;

    // 1024 blocks x 512 thr = 8192 waves; 2 rows/wave/iter x 4 iters = 65536.
    // (512,2): VGPR cap 128 >= demand -> zero scratch (R4/R7-proven shell).
    // R9 lever: softmax deleted (y-space select) + radix depth 28 -> 16.
    fused_mlp_topk<<<dim3(1024), dim3(THREADS), 0, stream>>>(x, W1, b1, W2, b2, W3, b3, out);
}

// Round 10
// 326.342 us; speedup vs baseline: 1.2490x; 1.2490x over previous
//
#include <hip/hip_runtime.h>
#include <math.h>

#define B_ROWS 65536
#define WDIM 512
#define HDIM 8
#define THREADS 512

// Native clang vector type — __builtin_nontemporal_{load,store} require it.
typedef float native_float4 __attribute__((ext_vector_type(4)));

// ---- DPP cross-lane (VALU pipe; avoids ds_swizzle latency/contention) ----
template<int CTRL, int ROWM>
__device__ __forceinline__ float dpp_mov(float oldv, float x) {
    return __int_as_float(__builtin_amdgcn_update_dpp(
        __float_as_int(oldv), __float_as_int(x), CTRL, ROWM, 0xF, false));
}

// Full-wave (64-lane) sum, broadcast via readlane(63). Order bit-exact vs R0.
__device__ __forceinline__ float wave_sum(float x) {
    x += dpp_mov<0x121, 0xF>(0.f, x);   // row_ror:1
    x += dpp_mov<0x122, 0xF>(0.f, x);   // row_ror:2
    x += dpp_mov<0x124, 0xF>(0.f, x);   // row_ror:4
    x += dpp_mov<0x128, 0xF>(0.f, x);   // row_ror:8  -> row-of-16 sums
    x += dpp_mov<0x142, 0xA>(0.f, x);   // row_bcast15
    x += dpp_mov<0x143, 0xC>(0.f, x);   // row_bcast31 -> lane63 = total
    return __int_as_float(__builtin_amdgcn_readlane(__float_as_int(x), 63));
}

__device__ __forceinline__ float dot8(native_float4 a0, native_float4 a1,
                                      native_float4 b0, native_float4 b1) {
    float s = a0.x * b0.x;
    s = fmaf(a0.y, b0.y, s); s = fmaf(a0.z, b0.z, s); s = fmaf(a0.w, b0.w, s);
    s = fmaf(a1.x, b1.x, s); s = fmaf(a1.y, b1.y, s);
    s = fmaf(a1.z, b1.z, s); s = fmaf(a1.w, b1.w, s);
    return s;
}

// Order-preserving float->uint: y1 < y2  <=>  ford(y1) < ford(y2) (unsigned).
__device__ __forceinline__ unsigned ford(float f) {
    unsigned b = __float_as_uint(f);
    return b ^ ((unsigned)((int)b >> 31) | 0x80000000u);
}

// Measured model (R0-R9):
//  - Occupancy steps only at VGPR 64/128 quanta; 2-row body (VGPR~104) = 4
//    waves/SIMD, and every <=64 attempt spills catastrophically. R7/R4 shell
//    (512,2) is the occupancy optimum.
//  - R9 (radix-4, 768 ballots) vs R7 (radix-2, 448): VALU-busy time constant,
//    stall +75us => the selection phase is BALLOT-COUNT-bound (VALU->SALU
//    round trips on the CU-shared scalar unit; homogeneous waves stall
//    together). Lever = TOTAL ballots, not step count.
// R10: y-space keys (no exp/max/div — monotone-equivalent, R9-verified
//  absmax 0.0) + radix-2 with EARLY EXIT: if count(u > c) == 14 exactly,
//  {u > c} IS the top-14 set (excluded elements <= c < min(set); boundary
//  ties make the count jump 13->15, never 14, and then fall through to the
//  full-descent path = R7's verified semantics). Continuous y => exits in
//  ~8-14 steps; expected ballots ~160/pair vs 448 (R7) / 768 (R9).
__global__ __launch_bounds__(THREADS, 2)
void fused_mlp_topk(const float* __restrict__ x,
                    const float* __restrict__ W1,
                    const float* __restrict__ b1,
                    const float* __restrict__ W2,
                    const float* __restrict__ b2,
                    const float* __restrict__ W3,
                    const float* __restrict__ b3,
                    float* __restrict__ out)
{
    // W1 as [j][i] (8x512), W3 transposed to [k][i] (8x512): compute reads are
    // 16B/lane stride-16B ds_read_b128 (conflict-free). One read serves 2 rows.
    __shared__ __align__(16) float sW1[HDIM * WDIM];
    __shared__ __align__(16) float sW3t[HDIM * WDIM];
    __shared__ __align__(16) float sb3[WDIM];

    const int tid = threadIdx.x;
    for (int i = tid; i < HDIM * WDIM; i += THREADS) sW1[i] = W1[i];
    for (int i = tid; i < HDIM * WDIM; i += THREADS) {
        int r = i >> 3, k = i & 7;          // W3 is (512,8) row-major
        sW3t[k * WDIM + r] = W3[i];
    }
    for (int i = tid; i < WDIM; i += THREADS) sb3[i] = b3[i];
    __syncthreads();

    const int lane = tid & 63;
    const int wave_id = blockIdx.x * (THREADS / 64) + (tid >> 6);   // 8192 waves

    const native_float4* sW1v = reinterpret_cast<const native_float4*>(sW1);
    const native_float4* sW3v = reinterpret_cast<const native_float4*>(sW3t);
    const native_float4* sb3v = reinterpret_cast<const native_float4*>(sb3);

    // Preload first row pair (rows ra, ra+1), non-temporal (read-once stream).
    int ra = wave_id * 2;
    const native_float4* xpa = reinterpret_cast<const native_float4*>(x + (size_t)ra * WDIM);
    const native_float4* xpb = xpa + (WDIM / 4);
    native_float4 xa0 = __builtin_nontemporal_load(xpa + lane);
    native_float4 xa1 = __builtin_nontemporal_load(xpa + lane + 64);
    native_float4 xb0 = __builtin_nontemporal_load(xpb + lane);
    native_float4 xb1 = __builtin_nontemporal_load(xpb + lane + 64);

    #pragma unroll 1
    for (int it = 0; it < 4; ++it) {        // 8192 waves * 2 rows * 4 = 65536
        // -------- layer 1: 8 dots of 512 per row; LDS reads shared --------
        float pa[HDIM], pb[HDIM];
        #pragma unroll
        for (int j = 0; j < HDIM; ++j) {
            native_float4 w0 = sW1v[j * 128 + lane];
            native_float4 w1 = sW1v[j * 128 + lane + 64];
            pa[j] = dot8(xa0, xa1, w0, w1);
            pb[j] = dot8(xb0, xb1, w0, w1);
        }
        float h1a[HDIM], h1b[HDIM];
        #pragma unroll
        for (int j = 0; j < HDIM; ++j) {
            float sa = wave_sum(pa[j]) + b1[j];
            float sb = wave_sum(pb[j]) + b1[j];
            h1a[j] = sa > 0.f ? sa : 0.f;
            h1b[j] = sb > 0.f ? sb : 0.f;
        }

        // -------- layer 2: 8x8, wave-uniform --------
        float h2a[HDIM], h2b[HDIM];
        #pragma unroll
        for (int j = 0; j < HDIM; ++j) {
            float va = b2[j], vb = b2[j];
            #pragma unroll
            for (int k = 0; k < HDIM; ++k) {
                const float w = W2[j * HDIM + k];
                va = fmaf(w, h1a[k], va);
                vb = fmaf(w, h1b[k], vb);
            }
            h2a[j] = va > 0.f ? va : 0.f;
            h2b[j] = vb > 0.f ? vb : 0.f;
        }

        // -------- layer 3: vector form -> per-element FMA (contracted),
        // packable into v_pk_fma_f32 --------
        native_float4 ya0 = sb3v[lane];
        native_float4 ya1 = sb3v[lane + 64];
        native_float4 yb0 = ya0, yb1 = ya1;
        #pragma unroll
        for (int k = 0; k < HDIM; ++k) {
            const float ha = h2a[k], hb = h2b[k];
            native_float4 w0 = sW3v[k * 128 + lane];
            native_float4 w1 = sW3v[k * 128 + lane + 64];
            ya0 += ha * w0;  ya1 += ha * w1;
            yb0 += hb * w0;  yb1 += hb * w1;
        }

        // -------- prefetch next pair's x (covered by radix select) -------
        const int nra = ra + 16384;         // 8192 waves * 2 rows sweep
        native_float4 nxa0, nxa1, nxb0, nxb1;
        if (it < 3) {
            const native_float4* nxpa = reinterpret_cast<const native_float4*>(x + (size_t)nra * WDIM);
            const native_float4* nxpb = nxpa + (WDIM / 4);
            nxa0 = __builtin_nontemporal_load(nxpa + lane);
            nxa1 = __builtin_nontemporal_load(nxpa + lane + 64);
            nxb0 = __builtin_nontemporal_load(nxpb + lane);
            nxb1 = __builtin_nontemporal_load(nxpb + lane + 64);
        }

        // -------- y-space top-k keys (no max/exp/div; R9-verified) --------
        unsigned ua[8], ub[8];
        ua[0] = ford(ya0.x); ua[1] = ford(ya0.y); ua[2] = ford(ya0.z); ua[3] = ford(ya0.w);
        ua[4] = ford(ya1.x); ua[5] = ford(ya1.y); ua[6] = ford(ya1.z); ua[7] = ford(ya1.w);
        ub[0] = ford(yb0.x); ub[1] = ford(yb0.y); ub[2] = ford(yb0.z); ub[3] = ford(yb0.w);
        ub[4] = ford(yb1.x); ub[5] = ford(yb1.y); ub[6] = ford(yb1.z); ub[7] = ford(yb1.w);
        if (lane == 0)  { ua[0] = 0u; ub[0] = 0u; }   // forced col 0 (excluded)
        if (lane == 63) { ua[7] = 0u; ub[7] = 0u; }   // forced col 511 (excluded)

        // -------- 14th-largest via radix-2 bit-search with early exit.
        // Invariant: count(u > Ua) >= 14. Set bit iff count(u > Ua|bit) >= 14.
        // EARLY EXIT: count == 14 exactly => {u > cand} is provably the
        // exact top-14 set (no boundary tie possible at count 14). Fallback
        // (no exit in 32 steps) == R7's full-descent verified semantics. ----
        unsigned Ua = 0u, Ub = 0u;
        unsigned tha = 0u, thb = 0u;        // resolved thresholds (0 = open)
        #pragma unroll 1
        for (int b = 31; b >= 0; --b) {
            const unsigned bit = 1u << b;
            if (!tha) {
                const unsigned cf = Ua | bit;
                int ca = 0;
                #pragma unroll
                for (int t = 0; t < 8; ++t)
                    ca += __popcll(__ballot(ua[t] > cf));
                if (ca == 14)      tha = cf + 1u;   // exact set isolated
                else if (ca > 14)  Ua = cf;
            }
            if (!thb) {
                const unsigned cf = Ub | bit;
                int cb = 0;
                #pragma unroll
                for (int t = 0; t < 8; ++t)
                    cb += __popcll(__ballot(ub[t] > cf));
                if (cb == 14)      thb = cf + 1u;
                else if (cb > 14)  Ub = cf;
            }
            if (tha && thb) break;
        }
        if (!tha) tha = Ua + 1u;            // full-descent fallback (ties)
        if (!thb) thb = Ub + 1u;

        // -------- emit 0/1 masks; forced cols overridden ----------
        native_float4 r0, r1, q0, q1;
        r0.x = ua[0] >= tha ? 1.f : 0.f;  r0.y = ua[1] >= tha ? 1.f : 0.f;
        r0.z = ua[2] >= tha ? 1.f : 0.f;  r0.w = ua[3] >= tha ? 1.f : 0.f;
        r1.x = ua[4] >= tha ? 1.f : 0.f;  r1.y = ua[5] >= tha ? 1.f : 0.f;
        r1.z = ua[6] >= tha ? 1.f : 0.f;  r1.w = ua[7] >= tha ? 1.f : 0.f;
        q0.x = ub[0] >= thb ? 1.f : 0.f;  q0.y = ub[1] >= thb ? 1.f : 0.f;
        q0.z = ub[2] >= thb ? 1.f : 0.f;  q0.w = ub[3] >= thb ? 1.f : 0.f;
        q1.x = ub[4] >= thb ? 1.f : 0.f;  q1.y = ub[5] >= thb ? 1.f : 0.f;
        q1.z = ub[6] >= thb ? 1.f : 0.f;  q1.w = ub[7] >= thb ? 1.f : 0.f;
        if (lane == 0)  { r0.x = 1.f; q0.x = 1.f; }
        if (lane == 63) { r1.w = 1.f; q1.w = 1.f; }

        native_float4* oa = reinterpret_cast<native_float4*>(out + (size_t)ra * WDIM);
        native_float4* ob = oa + (WDIM / 4);
        __builtin_nontemporal_store(r0, oa + lane);
        __builtin_nontemporal_store(r1, oa + lane + 64);
        __builtin_nontemporal_store(q0, ob + lane);
        __builtin_nontemporal_store(q1, ob + lane + 64);

        ra = nra;
        xa0 = nxa0; xa1 = nxa1; xb0 = nxb0; xb1 = nxb1;
    }
}

extern "C" void kernel_launch(void* const* d_in, const int* in_sizes, int n_in,
                              void* d_out, int out_size, void* d_ws, size_t ws_size,
                              hipStream_t stream) {
    const float* x  = (const float*)d_in[0];
    const float* W1 = (const float*)d_in[1];
    const float* b1 = (const float*)d_in[2];
    const float* W2 = (const float*)d_in[3];
    const float* b2 = (const float*)d_in[4];
    const float* W3 = (const float*)d_in[5];
    const float* b3 = (const float*)d_in[6];
    float* out = (float*)d_out;

    // 1024 blocks x 512 thr = 8192 waves; 2 rows/wave/iter x 4 iters = 65536.
    // (512,2): VGPR cap 128 >= demand -> zero scratch (R4/R7-proven shell).
    // R10 lever: ballot-count total (R9's proven bottleneck) cut ~3x via
    // early-exit radix-2 on y-space keys.
    fused_mlp_topk<<<dim3(1024), dim3(THREADS), 0, stream>>>(x, W1, b1, W2, b2, W3, b3, out);
}